// Round 9
// baseline (431.764 us; speedup 1.0000x reference)
//
#include <hip/hip_runtime.h>
#include <hip/hip_bf16.h>
#include <stdint.h>

#define NN 100000
#define NE 1600000
#define FIN 128
#define HID 64
#define COUT 16

#define NC 8                    // colors (sub-bins per node)
#define NBINS (NN * NC)         // 800000
#define SC 4                    // bins per thread in scan
#define SCAN_T 256
#define SCAN_SPAN (SCAN_T * SC) // 1024 bins per scan block
#define SCAN_NB ((NBINS + SCAN_SPAN - 1) / SCAN_SPAN)  // 782

#define MASK44 ((1ull << 44) - 1)

typedef unsigned long long u64;
typedef short bf16x8 __attribute__((ext_vector_type(8)));   // 8 bf16 in 4 VGPRs
typedef float f32x4 __attribute__((ext_vector_type(4)));

struct Flags { int f32; int i64; };

__device__ __forceinline__ float b2f(__hip_bfloat16 v) { return __bfloat162float(v); }

// adaptive float load: fp32 buffer or bf16 buffer
__device__ __forceinline__ float ldf(const void* p, size_t i, int f32) {
    return f32 ? ((const float*)p)[i]
               : __bfloat162float(((const __hip_bfloat16*)p)[i]);
}
// adaptive edge-index load: int32 or int64 buffer, logical index i in [0, 2*NE)
__device__ __forceinline__ int lde(const void* p, size_t i, int i64) {
    return i64 ? (int)((const long long*)p)[i] : ((const int*)p)[i];
}
// non-temporal (streaming) variants — bypass L2 allocation for one-shot streams
__device__ __forceinline__ float ldf_nt(const void* p, size_t i, int f32) {
    if (f32) return __builtin_nontemporal_load((const float*)p + i);
    unsigned short u = __builtin_nontemporal_load((const unsigned short*)p + i);
    union { unsigned int ui; float f; } v; v.ui = ((unsigned int)u) << 16;
    return v.f;
}
__device__ __forceinline__ int lde_nt(const void* p, size_t i, int i64) {
    return i64 ? (int)__builtin_nontemporal_load((const long long*)p + i)
               : __builtin_nontemporal_load((const int*)p + i);
}
// load 4 consecutive bf16 (8B-aligned) -> 4 floats
__device__ __forceinline__ void ld4bf(const __hip_bfloat16* p, float& x0, float& x1,
                                      float& x2, float& x3) {
    union { uint2 u; __hip_bfloat16 h[4]; } v;
    v.u = *(const uint2*)p;
    x0 = b2f(v.h[0]); x1 = b2f(v.h[1]); x2 = b2f(v.h[2]); x3 = b2f(v.h[3]);
}

// ---- K0: detect input dtypes on-device (one wave + ballot) ----
__global__ void k_detect(const unsigned short* xs, const int* ei32, Flags* fl) {
    int lane = threadIdx.x & 63;
    int huge = 0;
    for (int i = lane * 2; i < 1024; i += 128) {          // even 16-bit words of x
        int e = (xs[i] >> 7) & 0xFF;
        if (e >= 0xC0) huge = 1;   // fp32 low-halves have random exponents; bf16 N(0,1) never
    }
    int odd_nonzero = 0;
    for (int i = 1 + lane * 2; i < 512; i += 128) {       // odd int32 words of edge_index
        if (ei32[i] != 0) odd_nonzero = 1;                // int64 high words are all 0
    }
    u64 h = __ballot(huge), o = __ballot(odd_nonzero);
    if (lane == 0) { fl->f32 = (h != 0); fl->i64 = (o == 0); }
}

// ---- K1: packed per-(node,color) histogram: count<<44 | fixed-point weight sum ----
__global__ void k_hist(const void* __restrict__ ei, const void* __restrict__ ew,
                       const Flags* __restrict__ fl,
                       u64* __restrict__ hist8, u64* __restrict__ minkey) {
    int e = blockIdx.x * blockDim.x + threadIdx.x;
    if (e >= NE) return;
    int color = blockIdx.x & (NC - 1);
    int f32 = fl->f32, i64 = fl->i64;
    int r = lde_nt(ei, e, i64);
    int c = lde_nt(ei, (size_t)NE + e, i64);
    float w = ldf_nt(ew, e, f32);
    // w in [0,1]: w*2^32 exact in double (24-bit mantissa), < 2^33 << 2^44
    u64 add = (1ull << 44) | (u64)((double)w * 4294967296.0);
    atomicAdd(&hist8[(size_t)c * NC + color], add);
    if (r == 0) {
        u64 key = ((u64)__float_as_uint(w) << 32) | (unsigned)e;  // w>=0: bits monotone
        atomicMin(minkey, key);
    }
}

// ---- K2: dinv for both layers (deg recovered from fixed-point bins; exact) ----
__global__ void k_dinv(const u64* __restrict__ hist8, const void* __restrict__ ei,
                       const void* __restrict__ ew, const Flags* __restrict__ fl,
                       const u64* __restrict__ minkey,
                       float* __restrict__ dinv1, float* __restrict__ dinv2) {
    int i = blockIdx.x * blockDim.x + threadIdx.x;
    if (i >= NN) return;
    int f32 = fl->f32, i64 = fl->i64;
    u64 wsum = 0;
#pragma unroll
    for (int c = 0; c < NC; ++c) wsum += hist8[(size_t)i * NC + c] & MASK44;
    float deg = (float)((double)wsum * (1.0 / 4294967296.0));
    u64 k = *minkey;
    int eidx = (k == ~0ull) ? 0 : (int)(k & 0xffffffffu);  // argmin(all-inf)==0, like jnp
    int cmin = lde(ei, (size_t)NE + eidx, i64);
    float wmin = ldf(ew, eidx, f32);
    float d1 = deg + 1.0f;                    // +1 for self loop
    float d2 = d1 - ((i == cmin) ? wmin : 0.0f);
    dinv1[i] = rsqrtf(d1);
    dinv2[i] = rsqrtf(d2);
}

// ---- K3a: per-block local exclusive scan of bin counts ----
__global__ __launch_bounds__(SCAN_T) void k_scanA(const u64* __restrict__ hist8,
                                                  int* __restrict__ rowptrB,
                                                  int* __restrict__ blocksum) {
    __shared__ int sm[SCAN_T];
    int b = blockIdx.x, t = threadIdx.x;
    int base = b * SCAN_SPAN + t * SC;
    int v[SC];
    int s = 0;
#pragma unroll
    for (int j = 0; j < SC; ++j) {
        int idx = base + j;
        v[j] = (idx < NBINS) ? (int)(hist8[idx] >> 44) : 0;
        s += v[j];
    }
    sm[t] = s;
    for (int off = 1; off < SCAN_T; off <<= 1) {
        __syncthreads();
        int add = (t >= off) ? sm[t - off] : 0;
        __syncthreads();
        sm[t] += add;
    }
    __syncthreads();
    int run = sm[t] - s;  // exclusive prefix within block
#pragma unroll
    for (int j = 0; j < SC; ++j) {
        int idx = base + j;
        if (idx < NBINS) rowptrB[idx] = run;
        run += v[j];
    }
    if (t == SCAN_T - 1) blocksum[b] = sm[SCAN_T - 1];
}

// ---- K3b: scan the block sums (1 block, 1024 threads) ----
__global__ __launch_bounds__(1024) void k_scanB(const int* __restrict__ blocksum,
                                                int* __restrict__ blockoff,
                                                int* __restrict__ rowptrB) {
    __shared__ int sm[1024];
    int t = threadIdx.x;
    int v = (t < SCAN_NB) ? blocksum[t] : 0;
    sm[t] = v;
    for (int off = 1; off < 1024; off <<= 1) {
        __syncthreads();
        int add = (t >= off) ? sm[t - off] : 0;
        __syncthreads();
        sm[t] += add;
    }
    __syncthreads();
    if (t < SCAN_NB) blockoff[t] = sm[t] - v;     // exclusive block offset
    if (t == 1023) rowptrB[NBINS] = sm[1023];     // == NE
}

// ---- K3c: add block offsets ----
__global__ __launch_bounds__(SCAN_T) void k_scanC(const int* __restrict__ blockoff,
                                                  int* __restrict__ rowptrB) {
    int b = blockIdx.x, t = threadIdx.x;
    int base = b * SCAN_SPAN + t * SC;
    int off = blockoff[b];
#pragma unroll
    for (int j = 0; j < SC; ++j) {
        int idx = base + j;
        if (idx < NBINS) rowptrB[idx] += off;
    }
}

// ---- K4: placement — counting sort by (dest,color) bin, packed (src,w) ----
// epack scatter uses non-temporal store: no write-allocate RMW fetch per line.
__global__ void k_place(const void* __restrict__ ei, const void* __restrict__ ew,
                        const Flags* __restrict__ fl, const u64* __restrict__ minkey,
                        const int* __restrict__ rowptrB, int* __restrict__ cursorB,
                        int2* __restrict__ epack, int* __restrict__ delpos) {
    int e = blockIdx.x * blockDim.x + threadIdx.x;
    if (e >= NE) return;
    int color = blockIdx.x & (NC - 1);   // MUST match k_hist's color formula
    int f32 = fl->f32, i64 = fl->i64;
    int r = lde_nt(ei, e, i64);
    int c = lde_nt(ei, (size_t)NE + e, i64);
    float w = ldf_nt(ew, e, f32);
    int bin = c * NC + color;
    int pos = rowptrB[bin] + atomicAdd(&cursorB[bin], 1);
    // little-endian: low word -> .x (src), high word -> .y (w bits)
    long long pk = ((long long)__float_as_int(w) << 32) | (unsigned)r;
    __builtin_nontemporal_store(pk, (long long*)(epack + pos));
    u64 k = *minkey;
    int eidx = (k == ~0ull) ? 0 : (int)(k & 0xffffffffu);
    if (e == eidx) *delpos = pos;
}

// ---- K5a: fp32 path — LDS-tiled GEMM, 64 nodes x 64 cols per block ----
// ONE shared array, manually partitioned (round-7 bug: split arrays got
// reordered/eliminated by the LDS allocator — never assume adjacency).
__global__ __launch_bounds__(256) void k_gemm1_f32(const float* __restrict__ x,
                                                   const float* __restrict__ W1,
                                                   const Flags* __restrict__ fl,
                                                   __hip_bfloat16* __restrict__ h1) {
    if (!fl->f32) return;   // bf16 path handled by k_gemm1_mfma
    __shared__ float smem[16384];        // 64 KB: [0,8192)=W1, [8192,16384)=x tile
    float* Wp = smem;
    float* Xs = smem + 8192;
    int t = threadIdx.x;
    int node0 = blockIdx.x * 64;
    {   // stage W1 (8192 floats, float4)
        const float4* src = (const float4*)W1;
        float4* dst = (float4*)Wp;
        for (int i = t; i < 2048; i += 256) dst[i] = src[i];
    }
    {   // stage x tile (rows node0..node0+63 contiguous = 8192 floats)
        int xlim = (NN - node0) * (FIN / 4);           // valid float4 count
        if (xlim > 2048) xlim = 2048;
        const float4* src = (const float4*)(x + (size_t)node0 * FIN);
        float4* dst = (float4*)Xs;
        for (int i = t; i < xlim; i += 256) dst[i] = src[i];
    }
    __syncthreads();
    int col4 = (t & 15) * 4;
    int nb = t >> 4;                                   // 0..15
    float4 a0 = {0,0,0,0}, a1 = a0, a2 = a0, a3 = a0;
#pragma unroll 8
    for (int k = 0; k < FIN; k += 4) {
        float4 w0 = *(const float4*)&Wp[(k + 0) * HID + col4];
        float4 w1 = *(const float4*)&Wp[(k + 1) * HID + col4];
        float4 w2 = *(const float4*)&Wp[(k + 2) * HID + col4];
        float4 w3 = *(const float4*)&Wp[(k + 3) * HID + col4];
        float4 xv;
#define GEMM1_STEP(ACC, NOFF)                                            \
        xv = *(const float4*)&Xs[(nb + NOFF) * FIN + k];                 \
        ACC.x += xv.x * w0.x + xv.y * w1.x + xv.z * w2.x + xv.w * w3.x;  \
        ACC.y += xv.x * w0.y + xv.y * w1.y + xv.z * w2.y + xv.w * w3.y;  \
        ACC.z += xv.x * w0.z + xv.y * w1.z + xv.z * w2.z + xv.w * w3.z;  \
        ACC.w += xv.x * w0.w + xv.y * w1.w + xv.z * w2.w + xv.w * w3.w;
        GEMM1_STEP(a0, 0)
        GEMM1_STEP(a1, 16)
        GEMM1_STEP(a2, 32)
        GEMM1_STEP(a3, 48)
#undef GEMM1_STEP
    }
    float4 accs[4] = {a0, a1, a2, a3};
#pragma unroll
    for (int nn = 0; nn < 4; ++nn) {
        int node = node0 + nb + nn * 16;
        if (node < NN) {
            union { uint2 u; __hip_bfloat16 h[4]; } pk;
            pk.h[0] = __float2bfloat16(accs[nn].x);
            pk.h[1] = __float2bfloat16(accs[nn].y);
            pk.h[2] = __float2bfloat16(accs[nn].z);
            pk.h[3] = __float2bfloat16(accs[nn].w);
            *(uint2*)(h1 + (size_t)node * HID + col4) = pk.u;
        }
    }
}

// ---- K5b: bf16-input path (insurance; exits instantly when inputs are fp32) ----
__global__ __launch_bounds__(256) void k_gemm1_mfma(const __hip_bfloat16* __restrict__ x,
                                                    const unsigned short* __restrict__ W1,
                                                    const Flags* __restrict__ fl,
                                                    __hip_bfloat16* __restrict__ h1) {
    if (fl->f32) return;
    __shared__ unsigned short Wf[8192];  // [(n0*4+kc)*4+q][col*8+j]  16 KB
    int t = threadIdx.x;
    for (int i = t; i < 8192; i += 256) {
        int k = i >> 6;
        int n = i & 63;
        int kc = k >> 5, kr = k & 31;
        int q = kr >> 3, j = kr & 7;
        int n0 = n >> 4, col = n & 15;
        Wf[((((n0 << 2) | kc) << 2) | q) * 128 + col * 8 + j] = W1[i];
    }
    __syncthreads();
    int wave = t >> 6, lane = t & 63;
    int quad = lane >> 4, col = lane & 15;
    bf16x8 B[4][4];
#pragma unroll
    for (int n0 = 0; n0 < 4; ++n0)
#pragma unroll
        for (int kc = 0; kc < 4; ++kc)
            B[kc][n0] = *(const bf16x8*)&Wf[((((n0 << 2) | kc) << 2) | quad) * 128 + col * 8];
    int tile0 = (blockIdx.x * 4 + wave) * 4;
#pragma unroll 1
    for (int i = 0; i < 4; ++i) {
        int node0 = (tile0 + i) * 16;
        if (node0 >= NN) return;
        const __hip_bfloat16* xp = x + (size_t)(node0 + col) * FIN + quad * 8;
        f32x4 a0 = {0.f, 0.f, 0.f, 0.f}, a1 = a0, a2 = a0, a3 = a0;
#pragma unroll
        for (int kc = 0; kc < 4; ++kc) {
            bf16x8 A = *(const bf16x8*)(xp + kc * 32);
            a0 = __builtin_amdgcn_mfma_f32_16x16x32_bf16(A, B[kc][0], a0, 0, 0, 0);
            a1 = __builtin_amdgcn_mfma_f32_16x16x32_bf16(A, B[kc][1], a1, 0, 0, 0);
            a2 = __builtin_amdgcn_mfma_f32_16x16x32_bf16(A, B[kc][2], a2, 0, 0, 0);
            a3 = __builtin_amdgcn_mfma_f32_16x16x32_bf16(A, B[kc][3], a3, 0, 0, 0);
        }
        __hip_bfloat16* hp = h1 + (size_t)(node0 + quad * 4) * HID + col;
#pragma unroll
        for (int r = 0; r < 4; ++r) {
            hp[(size_t)r * HID + 0]  = __float2bfloat16(a0[r]);
            hp[(size_t)r * HID + 16] = __float2bfloat16(a1[r]);
            hp[(size_t)r * HID + 32] = __float2bfloat16(a2[r]);
            hp[(size_t)r * HID + 48] = __float2bfloat16(a3[r]);
        }
    }
}

// ---- K6: gather-aggregate layer 1, shfl-broadcast edge batching ----
// epack is streamed once -> non-temporal loads keep h1's gather set resident in L2.
__global__ __launch_bounds__(256) void k_agg1(const int* __restrict__ rowptrB,
                                              const int2* __restrict__ epack,
                                              const float* __restrict__ dinv1,
                                              const __hip_bfloat16* __restrict__ h1,
                                              const void* __restrict__ b1,
                                              const Flags* __restrict__ fl,
                                              float* __restrict__ out1) {
    int t = threadIdx.x;
    int n = blockIdx.x * 16 + (t >> 4);  // 16 nodes/block, 16 lanes/node
    if (n >= NN) return;
    int l = t & 15;
    int f = l * 4;
    int wbase = t & 48;                  // group base lane within wave
    int f32 = fl->f32;
    float dn = dinv1[n];
    int p0 = rowptrB[(size_t)n * NC], p1 = rowptrB[(size_t)(n + 1) * NC];
    float a0 = 0.f, a1 = 0.f, a2 = 0.f, a3 = 0.f;
    for (int p = p0; p < p1; p += 16) {
        int idx = p + l;
        int rsrc = 0;
        float cw = 0.f;
        if (idx < p1) {
            long long pk = __builtin_nontemporal_load((const long long*)(epack + idx));
            rsrc = (int)(unsigned)(pk & 0xffffffffu);
            cw = dinv1[rsrc] * __int_as_float((int)(pk >> 32));
        }
        int cnt = p1 - p; if (cnt > 16) cnt = 16;
        for (int j = 0; j < cnt; ++j) {
            int   r = __shfl(rsrc, wbase + j);
            float c = __shfl(cw,   wbase + j);
            float x0, x1, x2, x3;
            ld4bf(h1 + (size_t)r * HID + f, x0, x1, x2, x3);
            a0 += c * x0; a1 += c * x1; a2 += c * x2; a3 += c * x3;
        }
    }
    float x0, x1, x2, x3;
    ld4bf(h1 + (size_t)n * HID + f, x0, x1, x2, x3);
    float s = dn * dn;
    float4 o;
    o.x = fmaxf(dn * a0 + s * x0 + ldf(b1, f + 0, f32), 0.f);
    o.y = fmaxf(dn * a1 + s * x1 + ldf(b1, f + 1, f32), 0.f);
    o.z = fmaxf(dn * a2 + s * x2 + ldf(b1, f + 2, f32), 0.f);
    o.w = fmaxf(dn * a3 + s * x3 + ldf(b1, f + 3, f32), 0.f);
    *(float4*)(out1 + (size_t)n * HID + f) = o;
}

// ---- K7: h2 = out1 @ W2 ----
__global__ __launch_bounds__(256) void k_gemm2(const float* __restrict__ out1,
                                               const void* __restrict__ W2,
                                               const Flags* __restrict__ fl,
                                               float* __restrict__ h2) {
    __shared__ float Ws[HID * COUT];  // 4 KB
    int t = threadIdx.x;
    int f32 = fl->f32;
    for (int i = t; i < HID * COUT; i += 256) Ws[i] = ldf(W2, i, f32);
    __syncthreads();
    int node = blockIdx.x * 64 + (t >> 2);  // 64 nodes/block, 4 threads/node
    if (node >= NN) return;
    int o4 = (t & 3) * 4;
    const float* xr = out1 + (size_t)node * HID;
    float a0 = 0.f, a1 = 0.f, a2 = 0.f, a3 = 0.f;
#pragma unroll 4
    for (int k = 0; k < HID; ++k) {
        float xv = xr[k];
        const float* wr = &Ws[k * COUT + o4];
        a0 += xv * wr[0]; a1 += xv * wr[1]; a2 += xv * wr[2]; a3 += xv * wr[3];
    }
    float* ho = h2 + (size_t)node * COUT + o4;
    ho[0] = a0; ho[1] = a1; ho[2] = a2; ho[3] = a3;
}

// ---- K8: gather-aggregate layer 2, shfl-broadcast (4-lane groups) ----
__global__ __launch_bounds__(256) void k_agg2(const int* __restrict__ rowptrB,
                                              const int2* __restrict__ epack,
                                              const float* __restrict__ dinv2,
                                              const float* __restrict__ h2,
                                              const void* __restrict__ bias2,
                                              const Flags* __restrict__ fl,
                                              const int* __restrict__ delpos,
                                              void* __restrict__ out) {
    int t = threadIdx.x;
    int n = blockIdx.x * 64 + (t >> 2);  // 64 nodes/block, 4 lanes/node
    if (n >= NN) return;
    int l = t & 3;
    int f = l * 4;
    int wbase = t & 60;                  // group base lane within wave
    int f32 = fl->f32;
    int dp = *delpos;
    float dn = dinv2[n];
    int p0 = rowptrB[(size_t)n * NC], p1 = rowptrB[(size_t)(n + 1) * NC];
    float a0 = 0.f, a1 = 0.f, a2 = 0.f, a3 = 0.f;
    for (int p = p0; p < p1; p += 4) {
        int idx = p + l;
        int rr = 0;
        float cw = 0.f;
        if (idx < p1) {
            long long pk = __builtin_nontemporal_load((const long long*)(epack + idx));
            rr = (int)(unsigned)(pk & 0xffffffffu);
            float w = (idx == dp) ? 0.f : __int_as_float((int)(pk >> 32));
            cw = dinv2[rr] * w;
        }
        int cnt = p1 - p; if (cnt > 4) cnt = 4;
        for (int j = 0; j < cnt; ++j) {
            int   r = __shfl(rr, wbase + j);
            float c = __shfl(cw, wbase + j);
            const float4 hv = *(const float4*)(h2 + (size_t)r * COUT + f);
            a0 += c * hv.x; a1 += c * hv.y; a2 += c * hv.z; a3 += c * hv.w;
        }
    }
    float s = dn * dn;
    const float4 hn = *(const float4*)(h2 + (size_t)n * COUT + f);
    float o0 = dn * a0 + s * hn.x + ldf(bias2, f + 0, f32);
    float o1 = dn * a1 + s * hn.y + ldf(bias2, f + 1, f32);
    float o2 = dn * a2 + s * hn.z + ldf(bias2, f + 2, f32);
    float o3 = dn * a3 + s * hn.w + ldf(bias2, f + 3, f32);
    size_t idx = (size_t)n * COUT + f;
    if (f32) {
        float* op = (float*)out + idx;
        op[0] = o0; op[1] = o1; op[2] = o2; op[3] = o3;
    } else {
        union { uint2 u; __hip_bfloat16 h[4]; } pk;
        pk.h[0] = __float2bfloat16(o0); pk.h[1] = __float2bfloat16(o1);
        pk.h[2] = __float2bfloat16(o2); pk.h[3] = __float2bfloat16(o3);
        *(uint2*)((__hip_bfloat16*)out + idx) = pk.u;
    }
}

extern "C" void kernel_launch(void* const* d_in, const int* in_sizes, int n_in,
                              void* d_out, int out_size, void* d_ws, size_t ws_size,
                              hipStream_t stream) {
    const void* x  = d_in[0];
    const void* ei = d_in[1];
    const void* ew = d_in[2];
    const void* W1 = d_in[3];
    const void* b1 = d_in[4];
    const void* W2 = d_in[5];
    const void* b2 = d_in[6];

    // workspace layout: ~64.8 MB (h2 aliases hist8: hist8 dead after dinv/scanA,
    // h2 first written by k_gemm2 much later — safe on a single stream)
    char* wsb = (char*)d_ws;
    float* dinv1   = (float*)wsb;                      wsb += (size_t)NN * 4;
    float* dinv2   = (float*)wsb;                      wsb += (size_t)NN * 4;
    int*   rowptrB = (int*)wsb;                        wsb += (size_t)(NBINS + 1) * 4;
    int*   cursorB = (int*)wsb;                        wsb += (size_t)NBINS * 4;
    int*   blocksum= (int*)wsb;                        wsb += (size_t)SCAN_NB * 4;
    int*   blockoff= (int*)wsb;                        wsb += (size_t)SCAN_NB * 4;
    wsb = (char*)(((uintptr_t)wsb + 15) & ~(uintptr_t)15);
    u64*   hist8   = (u64*)wsb;                        // NBINS u64 = 6.4 MB ...
    float* h2      = (float*)wsb;                      wsb += (size_t)NBINS * 8;  // aliased
    int2*  epack   = (int2*)wsb;                       wsb += (size_t)NE * 8;
    __hip_bfloat16* h1 = (__hip_bfloat16*)wsb;         wsb += (size_t)NN * HID * 2;
    float* out1    = (float*)wsb;                      wsb += (size_t)NN * HID * 4;
    u64*   minkey  = (u64*)wsb;                        wsb += 8;
    Flags* fl      = (Flags*)wsb;                      wsb += 8;
    int*   delpos  = (int*)wsb;                        wsb += 8;

    hipMemsetAsync(hist8,   0, (size_t)NBINS * 8, stream);
    hipMemsetAsync(cursorB, 0, (size_t)NBINS * 4, stream);
    hipMemsetAsync(minkey, 0xFF, 8, stream);
    hipMemsetAsync(delpos, 0xFF, 4, stream);

    k_detect<<<1, 64, 0, stream>>>((const unsigned short*)x, (const int*)ei, fl);
    k_hist<<<(NE + 255) / 256, 256, 0, stream>>>(ei, ew, fl, hist8, minkey);
    k_dinv<<<(NN + 255) / 256, 256, 0, stream>>>(hist8, ei, ew, fl, minkey, dinv1, dinv2);
    k_scanA<<<SCAN_NB, SCAN_T, 0, stream>>>(hist8, rowptrB, blocksum);
    k_scanB<<<1, 1024, 0, stream>>>(blocksum, blockoff, rowptrB);
    k_scanC<<<SCAN_NB, SCAN_T, 0, stream>>>(blockoff, rowptrB);
    k_place<<<(NE + 255) / 256, 256, 0, stream>>>(ei, ew, fl, minkey, rowptrB, cursorB,
                                                  epack, delpos);
    k_gemm1_f32<<<(NN + 63) / 64, 256, 0, stream>>>((const float*)x, (const float*)W1,
                                                    fl, h1);
    k_gemm1_mfma<<<(NN / 16 + 15) / 16, 256, 0, stream>>>((const __hip_bfloat16*)x,
                                                          (const unsigned short*)W1, fl, h1);
    k_agg1<<<(NN + 15) / 16, 256, 0, stream>>>(rowptrB, epack, dinv1, h1, b1, fl, out1);
    k_gemm2<<<(NN + 63) / 64, 256, 0, stream>>>(out1, W2, fl, h2);
    k_agg2<<<(NN + 63) / 64, 256, 0, stream>>>(rowptrB, epack, dinv2, h2, b2, fl,
                                               delpos, d_out);
}

// Round 10
// 416.716 us; speedup vs baseline: 1.0361x; 1.0361x over previous
//
#include <hip/hip_runtime.h>
#include <hip/hip_bf16.h>
#include <stdint.h>

#define NN 100000
#define NE 1600000
#define FIN 128
#define HID 64
#define COUT 16

#define NC 8                    // colors (sub-bins per node)
#define NBINS (NN * NC)         // 800000
#define SC 4                    // bins per thread in scan
#define SCAN_T 256
#define SCAN_SPAN (SCAN_T * SC) // 1024 bins per scan block
#define SCAN_NB ((NBINS + SCAN_SPAN - 1) / SCAN_SPAN)  // 782

// two-phase placement
#define BUKSH 7                 // 128 nodes per bucket
#define NBUK ((NN + 127) >> BUKSH)        // 782 buckets
#define PART_NB 400             // phase-A blocks
#define EPB (NE / PART_NB)      // 4000 edges per phase-A block

#define MASK44 ((1ull << 44) - 1)

typedef unsigned long long u64;
typedef short bf16x8 __attribute__((ext_vector_type(8)));
typedef float f32x4 __attribute__((ext_vector_type(4)));

struct Flags { int f32; int i64; };

__device__ __forceinline__ float b2f(__hip_bfloat16 v) { return __bfloat162float(v); }

__device__ __forceinline__ float ldf(const void* p, size_t i, int f32) {
    return f32 ? ((const float*)p)[i]
               : __bfloat162float(((const __hip_bfloat16*)p)[i]);
}
__device__ __forceinline__ int lde(const void* p, size_t i, int i64) {
    return i64 ? (int)((const long long*)p)[i] : ((const int*)p)[i];
}
__device__ __forceinline__ void ld4bf(const __hip_bfloat16* p, float& x0, float& x1,
                                      float& x2, float& x3) {
    union { uint2 u; __hip_bfloat16 h[4]; } v;
    v.u = *(const uint2*)p;
    x0 = b2f(v.h[0]); x1 = b2f(v.h[1]); x2 = b2f(v.h[2]); x3 = b2f(v.h[3]);
}

// ---- K0: detect input dtypes on-device (one wave + ballot) ----
__global__ void k_detect(const unsigned short* xs, const int* ei32, Flags* fl) {
    int lane = threadIdx.x & 63;
    int huge = 0;
    for (int i = lane * 2; i < 1024; i += 128) {
        int e = (xs[i] >> 7) & 0xFF;
        if (e >= 0xC0) huge = 1;   // fp32 low-halves have random exponents; bf16 N(0,1) never
    }
    int odd_nonzero = 0;
    for (int i = 1 + lane * 2; i < 512; i += 128) {
        if (ei32[i] != 0) odd_nonzero = 1;                // int64 high words are all 0
    }
    u64 h = __ballot(huge), o = __ballot(odd_nonzero);
    if (lane == 0) { fl->f32 = (h != 0); fl->i64 = (o == 0); }
}

// ---- K1: packed per-(node,color) histogram: count<<44 | fixed-point weight sum ----
// color = blockIdx&7 == (e>>8)&7 — k_partA MUST use the same formula.
__global__ void k_hist(const void* __restrict__ ei, const void* __restrict__ ew,
                       const Flags* __restrict__ fl,
                       u64* __restrict__ hist8, u64* __restrict__ minkey) {
    int e = blockIdx.x * blockDim.x + threadIdx.x;
    if (e >= NE) return;
    int color = blockIdx.x & (NC - 1);
    int f32 = fl->f32, i64 = fl->i64;
    int r = lde(ei, e, i64);
    int c = lde(ei, (size_t)NE + e, i64);
    float w = ldf(ew, e, f32);
    u64 add = (1ull << 44) | (u64)((double)w * 4294967296.0);
    atomicAdd(&hist8[(size_t)c * NC + color], add);
    if (r == 0) {
        u64 key = ((u64)__float_as_uint(w) << 32) | (unsigned)e;  // w>=0: bits monotone
        atomicMin(minkey, key);
    }
}

// ---- K2: dinv for both layers ----
__global__ void k_dinv(const u64* __restrict__ hist8, const void* __restrict__ ei,
                       const void* __restrict__ ew, const Flags* __restrict__ fl,
                       const u64* __restrict__ minkey,
                       float* __restrict__ dinv1, float* __restrict__ dinv2) {
    int i = blockIdx.x * blockDim.x + threadIdx.x;
    if (i >= NN) return;
    int f32 = fl->f32, i64 = fl->i64;
    u64 wsum = 0;
#pragma unroll
    for (int c = 0; c < NC; ++c) wsum += hist8[(size_t)i * NC + c] & MASK44;
    float deg = (float)((double)wsum * (1.0 / 4294967296.0));
    u64 k = *minkey;
    int eidx = (k == ~0ull) ? 0 : (int)(k & 0xffffffffu);
    int cmin = lde(ei, (size_t)NE + eidx, i64);
    float wmin = ldf(ew, eidx, f32);
    float d1 = deg + 1.0f;
    float d2 = d1 - ((i == cmin) ? wmin : 0.0f);
    dinv1[i] = rsqrtf(d1);
    dinv2[i] = rsqrtf(d2);
}

// ---- K3a/b/c: 3-phase scan of bin counts -> rowptrB ----
__global__ __launch_bounds__(SCAN_T) void k_scanA(const u64* __restrict__ hist8,
                                                  int* __restrict__ rowptrB,
                                                  int* __restrict__ blocksum) {
    __shared__ int sm[SCAN_T];
    int b = blockIdx.x, t = threadIdx.x;
    int base = b * SCAN_SPAN + t * SC;
    int v[SC];
    int s = 0;
#pragma unroll
    for (int j = 0; j < SC; ++j) {
        int idx = base + j;
        v[j] = (idx < NBINS) ? (int)(hist8[idx] >> 44) : 0;
        s += v[j];
    }
    sm[t] = s;
    for (int off = 1; off < SCAN_T; off <<= 1) {
        __syncthreads();
        int add = (t >= off) ? sm[t - off] : 0;
        __syncthreads();
        sm[t] += add;
    }
    __syncthreads();
    int run = sm[t] - s;
#pragma unroll
    for (int j = 0; j < SC; ++j) {
        int idx = base + j;
        if (idx < NBINS) rowptrB[idx] = run;
        run += v[j];
    }
    if (t == SCAN_T - 1) blocksum[b] = sm[SCAN_T - 1];
}

__global__ __launch_bounds__(1024) void k_scanB(const int* __restrict__ blocksum,
                                                int* __restrict__ blockoff,
                                                int* __restrict__ rowptrB) {
    __shared__ int sm[1024];
    int t = threadIdx.x;
    int v = (t < SCAN_NB) ? blocksum[t] : 0;
    sm[t] = v;
    for (int off = 1; off < 1024; off <<= 1) {
        __syncthreads();
        int add = (t >= off) ? sm[t - off] : 0;
        __syncthreads();
        sm[t] += add;
    }
    __syncthreads();
    if (t < SCAN_NB) blockoff[t] = sm[t] - v;
    if (t == 1023) rowptrB[NBINS] = sm[1023];     // == NE
}

__global__ __launch_bounds__(SCAN_T) void k_scanC(const int* __restrict__ blockoff,
                                                  int* __restrict__ rowptrB) {
    int b = blockIdx.x, t = threadIdx.x;
    int base = b * SCAN_SPAN + t * SC;
    int off = blockoff[b];
#pragma unroll
    for (int j = 0; j < SC; ++j) {
        int idx = base + j;
        if (idx < NBINS) rowptrB[idx] += off;
    }
}

// ---- K4a: phase-A partition into 782 dest-buckets (block-local counting sort) ----
// tmp bucket base == rowptrB[bucket<<10] (bins are node-major, buckets contiguous).
// tmp record: low32 = src | binlow<<17 | delflag<<27 ; high32 = w bits.
__global__ __launch_bounds__(256) void k_partA(const void* __restrict__ ei,
                                               const void* __restrict__ ew,
                                               const Flags* __restrict__ fl,
                                               const u64* __restrict__ minkey,
                                               const int* __restrict__ rowptrB,
                                               int* __restrict__ cursorA,
                                               long long* __restrict__ tmp) {
    __shared__ int cnt[NBUK];
    __shared__ int base[NBUK];
    int b = blockIdx.x, t = threadIdx.x;
    int f32 = fl->f32, i64 = fl->i64;
    for (int i = t; i < NBUK; i += 256) cnt[i] = 0;
    __syncthreads();
    int e0 = b * EPB;
    for (int i = t; i < EPB; i += 256) {
        int c = lde(ei, (size_t)NE + e0 + i, i64);
        atomicAdd(&cnt[c >> BUKSH], 1);
    }
    __syncthreads();
    for (int i = t; i < NBUK; i += 256) {
        int n = cnt[i];
        base[i] = n ? (rowptrB[i << 10] + atomicAdd(&cursorA[i], n)) : 0;
    }
    __syncthreads();
    for (int i = t; i < NBUK; i += 256) cnt[i] = 0;
    __syncthreads();
    u64 k = *minkey;
    int eidx = (k == ~0ull) ? 0 : (int)(k & 0xffffffffu);
    for (int i = t; i < EPB; i += 256) {
        int e = e0 + i;
        int r = lde(ei, e, i64);
        int c = lde(ei, (size_t)NE + e, i64);
        float w = ldf(ew, e, f32);
        int buk = c >> BUKSH;
        int slot = atomicAdd(&cnt[buk], 1);
        unsigned binlow = (((unsigned)c & 127u) << 3) | (((unsigned)e >> 8) & 7u);
        unsigned lo = (unsigned)r | (binlow << 17) | ((e == eidx) ? (1u << 27) : 0u);
        long long pk = ((long long)__float_as_int(w) << 32) | lo;
        tmp[base[buk] + slot] = pk;
    }
}

// ---- K4b: phase-B final placement within bucket (LDS bin cursors, 16 KB window) ----
__global__ __launch_bounds__(256) void k_partB(const int* __restrict__ rowptrB,
                                               const long long* __restrict__ tmp,
                                               int2* __restrict__ epack,
                                               int* __restrict__ delpos) {
    __shared__ int cur[1024];
    int b = blockIdx.x, t = threadIdx.x;
    int binbase = b << 10;
    for (int i = t; i < 1024; i += 256) {
        int idx = binbase + i;
        cur[i] = rowptrB[idx > NBINS ? NBINS : idx];
    }
    __syncthreads();
    int s0 = rowptrB[binbase];
    int e1i = binbase + 1024; if (e1i > NBINS) e1i = NBINS;
    int s1 = rowptrB[e1i];
    for (int i = s0 + t; i < s1; i += 256) {
        long long pk = tmp[i];
        unsigned lo = (unsigned)pk;
        int wbits = (int)(pk >> 32);
        int src = (int)(lo & 0x1FFFFu);
        int binlow = (int)((lo >> 17) & 1023u);
        int pos = atomicAdd(&cur[binlow], 1);
        long long outpk = ((long long)wbits << 32) | (unsigned)src;  // .x=src .y=w
        *(long long*)(epack + pos) = outpk;
        if (lo & (1u << 27)) *delpos = pos;
    }
}

// ---- K5a: fp32 path — LDS-tiled GEMM, 64 nodes x 64 cols per block ----
__global__ __launch_bounds__(256) void k_gemm1_f32(const float* __restrict__ x,
                                                   const float* __restrict__ W1,
                                                   const Flags* __restrict__ fl,
                                                   __hip_bfloat16* __restrict__ h1) {
    if (!fl->f32) return;
    __shared__ float smem[16384];        // ONE array, manually partitioned (r7 lesson)
    float* Wp = smem;
    float* Xs = smem + 8192;
    int t = threadIdx.x;
    int node0 = blockIdx.x * 64;
    {
        const float4* src = (const float4*)W1;
        float4* dst = (float4*)Wp;
        for (int i = t; i < 2048; i += 256) dst[i] = src[i];
    }
    {
        int xlim = (NN - node0) * (FIN / 4);
        if (xlim > 2048) xlim = 2048;
        const float4* src = (const float4*)(x + (size_t)node0 * FIN);
        float4* dst = (float4*)Xs;
        for (int i = t; i < xlim; i += 256) dst[i] = src[i];
    }
    __syncthreads();
    int col4 = (t & 15) * 4;
    int nb = t >> 4;
    float4 a0 = {0,0,0,0}, a1 = a0, a2 = a0, a3 = a0;
#pragma unroll 8
    for (int k = 0; k < FIN; k += 4) {
        float4 w0 = *(const float4*)&Wp[(k + 0) * HID + col4];
        float4 w1 = *(const float4*)&Wp[(k + 1) * HID + col4];
        float4 w2 = *(const float4*)&Wp[(k + 2) * HID + col4];
        float4 w3 = *(const float4*)&Wp[(k + 3) * HID + col4];
        float4 xv;
#define GEMM1_STEP(ACC, NOFF)                                            \
        xv = *(const float4*)&Xs[(nb + NOFF) * FIN + k];                 \
        ACC.x += xv.x * w0.x + xv.y * w1.x + xv.z * w2.x + xv.w * w3.x;  \
        ACC.y += xv.x * w0.y + xv.y * w1.y + xv.z * w2.y + xv.w * w3.y;  \
        ACC.z += xv.x * w0.z + xv.y * w1.z + xv.z * w2.z + xv.w * w3.z;  \
        ACC.w += xv.x * w0.w + xv.y * w1.w + xv.z * w2.w + xv.w * w3.w;
        GEMM1_STEP(a0, 0)
        GEMM1_STEP(a1, 16)
        GEMM1_STEP(a2, 32)
        GEMM1_STEP(a3, 48)
#undef GEMM1_STEP
    }
    float4 accs[4] = {a0, a1, a2, a3};
#pragma unroll
    for (int nn = 0; nn < 4; ++nn) {
        int node = node0 + nb + nn * 16;
        if (node < NN) {
            union { uint2 u; __hip_bfloat16 h[4]; } pk;
            pk.h[0] = __float2bfloat16(accs[nn].x);
            pk.h[1] = __float2bfloat16(accs[nn].y);
            pk.h[2] = __float2bfloat16(accs[nn].z);
            pk.h[3] = __float2bfloat16(accs[nn].w);
            *(uint2*)(h1 + (size_t)node * HID + col4) = pk.u;
        }
    }
}

// ---- K5b: bf16-input path (insurance; exits instantly when inputs are fp32) ----
__global__ __launch_bounds__(256) void k_gemm1_mfma(const __hip_bfloat16* __restrict__ x,
                                                    const unsigned short* __restrict__ W1,
                                                    const Flags* __restrict__ fl,
                                                    __hip_bfloat16* __restrict__ h1) {
    if (fl->f32) return;
    __shared__ unsigned short Wf[8192];
    int t = threadIdx.x;
    for (int i = t; i < 8192; i += 256) {
        int k = i >> 6;
        int n = i & 63;
        int kc = k >> 5, kr = k & 31;
        int q = kr >> 3, j = kr & 7;
        int n0 = n >> 4, col = n & 15;
        Wf[((((n0 << 2) | kc) << 2) | q) * 128 + col * 8 + j] = W1[i];
    }
    __syncthreads();
    int wave = t >> 6, lane = t & 63;
    int quad = lane >> 4, col = lane & 15;
    bf16x8 B[4][4];
#pragma unroll
    for (int n0 = 0; n0 < 4; ++n0)
#pragma unroll
        for (int kc = 0; kc < 4; ++kc)
            B[kc][n0] = *(const bf16x8*)&Wf[((((n0 << 2) | kc) << 2) | quad) * 128 + col * 8];
    int tile0 = (blockIdx.x * 4 + wave) * 4;
#pragma unroll 1
    for (int i = 0; i < 4; ++i) {
        int node0 = (tile0 + i) * 16;
        if (node0 >= NN) return;
        const __hip_bfloat16* xp = x + (size_t)(node0 + col) * FIN + quad * 8;
        f32x4 a0 = {0.f, 0.f, 0.f, 0.f}, a1 = a0, a2 = a0, a3 = a0;
#pragma unroll
        for (int kc = 0; kc < 4; ++kc) {
            bf16x8 A = *(const bf16x8*)(xp + kc * 32);
            a0 = __builtin_amdgcn_mfma_f32_16x16x32_bf16(A, B[kc][0], a0, 0, 0, 0);
            a1 = __builtin_amdgcn_mfma_f32_16x16x32_bf16(A, B[kc][1], a1, 0, 0, 0);
            a2 = __builtin_amdgcn_mfma_f32_16x16x32_bf16(A, B[kc][2], a2, 0, 0, 0);
            a3 = __builtin_amdgcn_mfma_f32_16x16x32_bf16(A, B[kc][3], a3, 0, 0, 0);
        }
        __hip_bfloat16* hp = h1 + (size_t)(node0 + quad * 4) * HID + col;
#pragma unroll
        for (int r = 0; r < 4; ++r) {
            hp[(size_t)r * HID + 0]  = __float2bfloat16(a0[r]);
            hp[(size_t)r * HID + 16] = __float2bfloat16(a1[r]);
            hp[(size_t)r * HID + 32] = __float2bfloat16(a2[r]);
            hp[(size_t)r * HID + 48] = __float2bfloat16(a3[r]);
        }
    }
}

// ---- K6: gather-aggregate layer 1, shfl-broadcast edge batching ----
__global__ __launch_bounds__(256) void k_agg1(const int* __restrict__ rowptrB,
                                              const int2* __restrict__ epack,
                                              const float* __restrict__ dinv1,
                                              const __hip_bfloat16* __restrict__ h1,
                                              const void* __restrict__ b1,
                                              const Flags* __restrict__ fl,
                                              float* __restrict__ out1) {
    int t = threadIdx.x;
    int n = blockIdx.x * 16 + (t >> 4);
    if (n >= NN) return;
    int l = t & 15;
    int f = l * 4;
    int wbase = t & 48;
    int f32 = fl->f32;
    float dn = dinv1[n];
    int p0 = rowptrB[(size_t)n * NC], p1 = rowptrB[(size_t)(n + 1) * NC];
    float a0 = 0.f, a1 = 0.f, a2 = 0.f, a3 = 0.f;
    for (int p = p0; p < p1; p += 16) {
        int idx = p + l;
        int2 ev = make_int2(0, 0);
        float cw = 0.f;
        if (idx < p1) {
            ev = epack[idx];
            cw = dinv1[ev.x] * __int_as_float(ev.y);
        }
        int cnt = p1 - p; if (cnt > 16) cnt = 16;
        for (int j = 0; j < cnt; ++j) {
            int   r = __shfl(ev.x, wbase + j);
            float c = __shfl(cw,   wbase + j);
            float x0, x1, x2, x3;
            ld4bf(h1 + (size_t)r * HID + f, x0, x1, x2, x3);
            a0 += c * x0; a1 += c * x1; a2 += c * x2; a3 += c * x3;
        }
    }
    float x0, x1, x2, x3;
    ld4bf(h1 + (size_t)n * HID + f, x0, x1, x2, x3);
    float s = dn * dn;
    float4 o;
    o.x = fmaxf(dn * a0 + s * x0 + ldf(b1, f + 0, f32), 0.f);
    o.y = fmaxf(dn * a1 + s * x1 + ldf(b1, f + 1, f32), 0.f);
    o.z = fmaxf(dn * a2 + s * x2 + ldf(b1, f + 2, f32), 0.f);
    o.w = fmaxf(dn * a3 + s * x3 + ldf(b1, f + 3, f32), 0.f);
    *(float4*)(out1 + (size_t)n * HID + f) = o;
}

// ---- K7: h2 = out1 @ W2 ----
__global__ __launch_bounds__(256) void k_gemm2(const float* __restrict__ out1,
                                               const void* __restrict__ W2,
                                               const Flags* __restrict__ fl,
                                               float* __restrict__ h2) {
    __shared__ float Ws[HID * COUT];
    int t = threadIdx.x;
    int f32 = fl->f32;
    for (int i = t; i < HID * COUT; i += 256) Ws[i] = ldf(W2, i, f32);
    __syncthreads();
    int node = blockIdx.x * 64 + (t >> 2);
    if (node >= NN) return;
    int o4 = (t & 3) * 4;
    const float* xr = out1 + (size_t)node * HID;
    float a0 = 0.f, a1 = 0.f, a2 = 0.f, a3 = 0.f;
#pragma unroll 4
    for (int k = 0; k < HID; ++k) {
        float xv = xr[k];
        const float* wr = &Ws[k * COUT + o4];
        a0 += xv * wr[0]; a1 += xv * wr[1]; a2 += xv * wr[2]; a3 += xv * wr[3];
    }
    float* ho = h2 + (size_t)node * COUT + o4;
    ho[0] = a0; ho[1] = a1; ho[2] = a2; ho[3] = a3;
}

// ---- K8: gather-aggregate layer 2, shfl-broadcast (4-lane groups) ----
__global__ __launch_bounds__(256) void k_agg2(const int* __restrict__ rowptrB,
                                              const int2* __restrict__ epack,
                                              const float* __restrict__ dinv2,
                                              const float* __restrict__ h2,
                                              const void* __restrict__ bias2,
                                              const Flags* __restrict__ fl,
                                              const int* __restrict__ delpos,
                                              void* __restrict__ out) {
    int t = threadIdx.x;
    int n = blockIdx.x * 64 + (t >> 2);
    if (n >= NN) return;
    int l = t & 3;
    int f = l * 4;
    int wbase = t & 60;
    int f32 = fl->f32;
    int dp = *delpos;
    float dn = dinv2[n];
    int p0 = rowptrB[(size_t)n * NC], p1 = rowptrB[(size_t)(n + 1) * NC];
    float a0 = 0.f, a1 = 0.f, a2 = 0.f, a3 = 0.f;
    for (int p = p0; p < p1; p += 4) {
        int idx = p + l;
        int rr = 0;
        float cw = 0.f;
        if (idx < p1) {
            int2 ev = epack[idx];
            float w = (idx == dp) ? 0.f : __int_as_float(ev.y);
            rr = ev.x;
            cw = dinv2[rr] * w;
        }
        int cnt = p1 - p; if (cnt > 4) cnt = 4;
        for (int j = 0; j < cnt; ++j) {
            int   r = __shfl(rr, wbase + j);
            float c = __shfl(cw, wbase + j);
            const float4 hv = *(const float4*)(h2 + (size_t)r * COUT + f);
            a0 += c * hv.x; a1 += c * hv.y; a2 += c * hv.z; a3 += c * hv.w;
        }
    }
    float s = dn * dn;
    const float4 hn = *(const float4*)(h2 + (size_t)n * COUT + f);
    float o0 = dn * a0 + s * hn.x + ldf(bias2, f + 0, f32);
    float o1 = dn * a1 + s * hn.y + ldf(bias2, f + 1, f32);
    float o2 = dn * a2 + s * hn.z + ldf(bias2, f + 2, f32);
    float o3 = dn * a3 + s * hn.w + ldf(bias2, f + 3, f32);
    size_t idx = (size_t)n * COUT + f;
    if (f32) {
        float* op = (float*)out + idx;
        op[0] = o0; op[1] = o1; op[2] = o2; op[3] = o3;
    } else {
        union { uint2 u; __hip_bfloat16 h[4]; } pk;
        pk.h[0] = __float2bfloat16(o0); pk.h[1] = __float2bfloat16(o1);
        pk.h[2] = __float2bfloat16(o2); pk.h[3] = __float2bfloat16(o3);
        *(uint2*)((__hip_bfloat16*)out + idx) = pk.u;
    }
}

extern "C" void kernel_launch(void* const* d_in, const int* in_sizes, int n_in,
                              void* d_out, int out_size, void* d_ws, size_t ws_size,
                              hipStream_t stream) {
    const void* x  = d_in[0];
    const void* ei = d_in[1];
    const void* ew = d_in[2];
    const void* W1 = d_in[3];
    const void* b1 = d_in[4];
    const void* W2 = d_in[5];
    const void* b2 = d_in[6];

    // workspace ~62 MB. Aliases (single stream, ordered):
    //   h2 over hist8 (hist8 dead after dinv/scanA; h2 written by gemm2 later)
    //   tmp (12.8 MB) over out1 (tmp dead after partB; out1 written by agg1 later)
    char* wsb = (char*)d_ws;
    float* dinv1   = (float*)wsb;                      wsb += (size_t)NN * 4;
    float* dinv2   = (float*)wsb;                      wsb += (size_t)NN * 4;
    int*   rowptrB = (int*)wsb;                        wsb += (size_t)(NBINS + 1) * 4;
    int*   cursorA = (int*)wsb;                        wsb += (size_t)NBUK * 4;
    int*   blocksum= (int*)wsb;                        wsb += (size_t)SCAN_NB * 4;
    int*   blockoff= (int*)wsb;                        wsb += (size_t)SCAN_NB * 4;
    wsb = (char*)(((uintptr_t)wsb + 15) & ~(uintptr_t)15);
    u64*   hist8   = (u64*)wsb;
    float* h2      = (float*)wsb;                      wsb += (size_t)NBINS * 8;
    int2*  epack   = (int2*)wsb;                       wsb += (size_t)NE * 8;
    __hip_bfloat16* h1 = (__hip_bfloat16*)wsb;         wsb += (size_t)NN * HID * 2;
    long long* tmp = (long long*)wsb;                  // aliased with out1 (12.8 of 25.6 MB)
    float* out1    = (float*)wsb;                      wsb += (size_t)NN * HID * 4;
    u64*   minkey  = (u64*)wsb;                        wsb += 8;
    Flags* fl      = (Flags*)wsb;                      wsb += 8;
    int*   delpos  = (int*)wsb;                        wsb += 8;

    hipMemsetAsync(hist8,   0, (size_t)NBINS * 8, stream);
    hipMemsetAsync(cursorA, 0, (size_t)NBUK * 4, stream);
    hipMemsetAsync(minkey, 0xFF, 8, stream);
    hipMemsetAsync(delpos, 0xFF, 4, stream);

    k_detect<<<1, 64, 0, stream>>>((const unsigned short*)x, (const int*)ei, fl);
    k_hist<<<(NE + 255) / 256, 256, 0, stream>>>(ei, ew, fl, hist8, minkey);
    k_dinv<<<(NN + 255) / 256, 256, 0, stream>>>(hist8, ei, ew, fl, minkey, dinv1, dinv2);
    k_scanA<<<SCAN_NB, SCAN_T, 0, stream>>>(hist8, rowptrB, blocksum);
    k_scanB<<<1, 1024, 0, stream>>>(blocksum, blockoff, rowptrB);
    k_scanC<<<SCAN_NB, SCAN_T, 0, stream>>>(blockoff, rowptrB);
    k_partA<<<PART_NB, 256, 0, stream>>>(ei, ew, fl, minkey, rowptrB, cursorA, tmp);
    k_partB<<<NBUK, 256, 0, stream>>>(rowptrB, tmp, epack, delpos);
    k_gemm1_f32<<<(NN + 63) / 64, 256, 0, stream>>>((const float*)x, (const float*)W1,
                                                    fl, h1);
    k_gemm1_mfma<<<(NN / 16 + 15) / 16, 256, 0, stream>>>((const __hip_bfloat16*)x,
                                                          (const unsigned short*)W1, fl, h1);
    k_agg1<<<(NN + 15) / 16, 256, 0, stream>>>(rowptrB, epack, dinv1, h1, b1, fl, out1);
    k_gemm2<<<(NN + 63) / 64, 256, 0, stream>>>(out1, W2, fl, h2);
    k_agg2<<<(NN + 63) / 64, 256, 0, stream>>>(rowptrB, epack, dinv2, h2, b2, fl,
                                               delpos, d_out);
}

// Round 11
// 324.419 us; speedup vs baseline: 1.3309x; 1.2845x over previous
//
#include <hip/hip_runtime.h>
#include <hip/hip_bf16.h>
#include <stdint.h>

#define NN 100000
#define NE 1600000
#define FIN 128
#define HID 64
#define COUT 16

// two-phase placement: coarse bucket = 256 dest nodes
#define BUKSH 8
#define BUKN 256
#define NBUK ((NN + BUKN - 1) >> BUKSH)   // 391
#define CAP 5120                          // slab capacity: mean 4096 + 16 sigma
#define PART_NB 200                       // phase-A blocks
#define EPB (NE / PART_NB)                // 8000 edges per phase-A block

typedef unsigned long long u64;
typedef short bf16x8 __attribute__((ext_vector_type(8)));
typedef float f32x4 __attribute__((ext_vector_type(4)));

struct Flags { int f32; int i64; };

__device__ __forceinline__ float b2f(__hip_bfloat16 v) { return __bfloat162float(v); }

__device__ __forceinline__ float ldf(const void* p, size_t i, int f32) {
    return f32 ? ((const float*)p)[i]
               : __bfloat162float(((const __hip_bfloat16*)p)[i]);
}
__device__ __forceinline__ int lde(const void* p, size_t i, int i64) {
    return i64 ? (int)((const long long*)p)[i] : ((const int*)p)[i];
}
__device__ __forceinline__ void ld4bf(const __hip_bfloat16* p, float& x0, float& x1,
                                      float& x2, float& x3) {
    union { uint2 u; __hip_bfloat16 h[4]; } v;
    v.u = *(const uint2*)p;
    x0 = b2f(v.h[0]); x1 = b2f(v.h[1]); x2 = b2f(v.h[2]); x3 = b2f(v.h[3]);
}

// ---- K0: detect input dtypes on-device (one wave + ballot) ----
__global__ void k_detect(const unsigned short* xs, const int* ei32, Flags* fl) {
    int lane = threadIdx.x & 63;
    int huge = 0;
    for (int i = lane * 2; i < 1024; i += 128) {
        int e = (xs[i] >> 7) & 0xFF;
        if (e >= 0xC0) huge = 1;   // fp32 low-halves have random exponents; bf16 N(0,1) never
    }
    int odd_nonzero = 0;
    for (int i = 1 + lane * 2; i < 512; i += 128) {
        if (ei32[i] != 0) odd_nonzero = 1;                // int64 high words are all 0
    }
    u64 h = __ballot(huge), o = __ballot(odd_nonzero);
    if (lane == 0) { fl->f32 = (h != 0); fl->i64 = (o == 0); }
}

// ---- K1: argmin over edges with row==0 (atomics only on the rare hit) ----
__global__ void k_mink(const void* __restrict__ ei, const void* __restrict__ ew,
                       const Flags* __restrict__ fl, u64* __restrict__ minkey) {
    int e = blockIdx.x * blockDim.x + threadIdx.x;
    if (e >= NE) return;
    int r = lde(ei, e, fl->i64);
    if (r == 0) {
        float w = ldf(ew, e, fl->f32);
        u64 key = ((u64)__float_as_uint(w) << 32) | (unsigned)e;  // w>=0: bits monotone
        atomicMin(minkey, key);
    }
}

// ---- K2: phase-A — partition edges into 391 coarse buckets (LDS histogram) ----
// tmp record: low32 = src(17b) | nodeLow(8b)<<17 | delflag<<25 ; high32 = w bits
__global__ __launch_bounds__(256) void k_partA(const void* __restrict__ ei,
                                               const void* __restrict__ ew,
                                               const Flags* __restrict__ fl,
                                               const u64* __restrict__ minkey,
                                               int* __restrict__ cursorA,
                                               long long* __restrict__ tmp) {
    __shared__ int cnt[NBUK];
    __shared__ int base[NBUK];
    int b = blockIdx.x, t = threadIdx.x;
    int f32 = fl->f32, i64 = fl->i64;
    for (int i = t; i < NBUK; i += 256) cnt[i] = 0;
    __syncthreads();
    int e0 = b * EPB;
    for (int i = t; i < EPB; i += 256) {
        int c = lde(ei, (size_t)NE + e0 + i, i64);
        atomicAdd(&cnt[c >> BUKSH], 1);
    }
    __syncthreads();
    for (int i = t; i < NBUK; i += 256) {
        int n = cnt[i];
        base[i] = n ? atomicAdd(&cursorA[i], n) : 0;   // 78K global atomics total
    }
    __syncthreads();
    for (int i = t; i < NBUK; i += 256) cnt[i] = 0;
    __syncthreads();
    u64 k = *minkey;
    int eidx = (k == ~0ull) ? 0 : (int)(k & 0xffffffffu);  // argmin(all-inf)==0, like jnp
    for (int i = t; i < EPB; i += 256) {
        int e = e0 + i;
        int r = lde(ei, e, i64);
        int c = lde(ei, (size_t)NE + e, i64);
        float w = ldf(ew, e, f32);
        int buk = c >> BUKSH;
        int slot = base[buk] + atomicAdd(&cnt[buk], 1);
        if (slot < CAP) {   // never triggers (16-sigma slack); guard vs OOB only
            unsigned lo = (unsigned)r | (((unsigned)c & 255u) << 17)
                        | ((e == eidx) ? (1u << 25) : 0u);
            tmp[(size_t)buk * CAP + slot] = ((long long)__float_as_int(w) << 32) | lo;
        }
    }
}

// ---- K3: scan 391 bucket totals -> bucket bases in epack; rowptrN[NN]=NE ----
__global__ __launch_bounds__(512) void k_scanBk(const int* __restrict__ cursorA,
                                                int* __restrict__ bucketBase,
                                                int* __restrict__ rowptrN) {
    __shared__ int sm[512];
    int t = threadIdx.x;
    int v = 0;
    if (t < NBUK) { v = cursorA[t]; if (v > CAP) v = CAP; }
    sm[t] = v;
    for (int off = 1; off < 512; off <<= 1) {
        __syncthreads();
        int add = (t >= off) ? sm[t - off] : 0;
        __syncthreads();
        sm[t] += add;
    }
    __syncthreads();
    if (t < NBUK) bucketBase[t] = sm[t] - v;
    if (t == 511) rowptrN[NN] = sm[511];   // == NE
}

// ---- K4: phase-B — per-bucket CSR build entirely in LDS ----
// counts + exact fixed-point weight sums + 256-scan + placement in an L2 window.
__global__ __launch_bounds__(256) void k_partB(const int* __restrict__ cursorA,
                                               const int* __restrict__ bucketBase,
                                               const long long* __restrict__ tmp,
                                               int2* __restrict__ epack,
                                               int* __restrict__ rowptrN,
                                               float* __restrict__ deg,
                                               int* __restrict__ delpos) {
    __shared__ int cnt[256];
    __shared__ int pfx[256];
    __shared__ u64 wsum[256];
    int b = blockIdx.x, t = threadIdx.x;
    cnt[t] = 0; wsum[t] = 0;
    __syncthreads();
    int count = cursorA[b]; if (count > CAP) count = CAP;
    const long long* ts = tmp + (size_t)b * CAP;
    for (int i = t; i < count; i += 256) {
        long long pk = ts[i];
        unsigned lo = (unsigned)pk;
        int nl = (int)((lo >> 17) & 255u);
        atomicAdd(&cnt[nl], 1);
        float w = __int_as_float((int)(pk >> 32));
        // w in [0,1]: w*2^32 exact in double — deg stays deterministic/exact
        atomicAdd(&wsum[nl], (u64)((double)w * 4294967296.0));
    }
    __syncthreads();
    int v = cnt[t];
    pfx[t] = v;
    for (int off = 1; off < 256; off <<= 1) {
        __syncthreads();
        int add = (t >= off) ? pfx[t - off] : 0;
        __syncthreads();
        pfx[t] += add;
    }
    __syncthreads();
    int excl = pfx[t] - v;
    int gbase = bucketBase[b];
    int node = (b << BUKSH) + t;
    if (node < NN) {
        rowptrN[node] = gbase + excl;
        deg[node] = (float)((double)wsum[t] * (1.0 / 4294967296.0));
    }
    __syncthreads();
    cnt[t] = gbase + excl;       // reuse as global write cursor
    __syncthreads();
    for (int i = t; i < count; i += 256) {
        long long pk = ts[i];
        unsigned lo = (unsigned)pk;
        int nl = (int)((lo >> 17) & 255u);
        int pos = atomicAdd(&cnt[nl], 1);
        long long outpk = (pk & 0xFFFFFFFF00000000LL) | (lo & 0x1FFFFu);  // .x=src .y=w
        *(long long*)(epack + pos) = outpk;
        if (lo & (1u << 25)) *delpos = pos;
    }
}

// ---- K5: dinv for both layers ----
__global__ void k_dinv(const float* __restrict__ deg, const void* __restrict__ ei,
                       const void* __restrict__ ew, const Flags* __restrict__ fl,
                       const u64* __restrict__ minkey,
                       float* __restrict__ dinv1, float* __restrict__ dinv2) {
    int i = blockIdx.x * blockDim.x + threadIdx.x;
    if (i >= NN) return;
    u64 k = *minkey;
    int eidx = (k == ~0ull) ? 0 : (int)(k & 0xffffffffu);
    int cmin = lde(ei, (size_t)NE + eidx, fl->i64);
    float wmin = ldf(ew, eidx, fl->f32);
    float d1 = deg[i] + 1.0f;                 // +1 for self loop
    float d2 = d1 - ((i == cmin) ? wmin : 0.0f);
    dinv1[i] = rsqrtf(d1);
    dinv2[i] = rsqrtf(d2);
}

// ---- K6a: fp32 path — LDS-tiled GEMM, 64 nodes x 64 cols per block ----
__global__ __launch_bounds__(256) void k_gemm1_f32(const float* __restrict__ x,
                                                   const float* __restrict__ W1,
                                                   const Flags* __restrict__ fl,
                                                   __hip_bfloat16* __restrict__ h1) {
    if (!fl->f32) return;
    __shared__ float smem[16384];        // ONE array, manually partitioned (r7 lesson)
    float* Wp = smem;
    float* Xs = smem + 8192;
    int t = threadIdx.x;
    int node0 = blockIdx.x * 64;
    {
        const float4* src = (const float4*)W1;
        float4* dst = (float4*)Wp;
        for (int i = t; i < 2048; i += 256) dst[i] = src[i];
    }
    {
        int xlim = (NN - node0) * (FIN / 4);
        if (xlim > 2048) xlim = 2048;
        const float4* src = (const float4*)(x + (size_t)node0 * FIN);
        float4* dst = (float4*)Xs;
        for (int i = t; i < xlim; i += 256) dst[i] = src[i];
    }
    __syncthreads();
    int col4 = (t & 15) * 4;
    int nb = t >> 4;
    float4 a0 = {0,0,0,0}, a1 = a0, a2 = a0, a3 = a0;
#pragma unroll 8
    for (int k = 0; k < FIN; k += 4) {
        float4 w0 = *(const float4*)&Wp[(k + 0) * HID + col4];
        float4 w1 = *(const float4*)&Wp[(k + 1) * HID + col4];
        float4 w2 = *(const float4*)&Wp[(k + 2) * HID + col4];
        float4 w3 = *(const float4*)&Wp[(k + 3) * HID + col4];
        float4 xv;
#define GEMM1_STEP(ACC, NOFF)                                            \
        xv = *(const float4*)&Xs[(nb + NOFF) * FIN + k];                 \
        ACC.x += xv.x * w0.x + xv.y * w1.x + xv.z * w2.x + xv.w * w3.x;  \
        ACC.y += xv.x * w0.y + xv.y * w1.y + xv.z * w2.y + xv.w * w3.y;  \
        ACC.z += xv.x * w0.z + xv.y * w1.z + xv.z * w2.z + xv.w * w3.z;  \
        ACC.w += xv.x * w0.w + xv.y * w1.w + xv.z * w2.w + xv.w * w3.w;
        GEMM1_STEP(a0, 0)
        GEMM1_STEP(a1, 16)
        GEMM1_STEP(a2, 32)
        GEMM1_STEP(a3, 48)
#undef GEMM1_STEP
    }
    float4 accs[4] = {a0, a1, a2, a3};
#pragma unroll
    for (int nn = 0; nn < 4; ++nn) {
        int node = node0 + nb + nn * 16;
        if (node < NN) {
            union { uint2 u; __hip_bfloat16 h[4]; } pk;
            pk.h[0] = __float2bfloat16(accs[nn].x);
            pk.h[1] = __float2bfloat16(accs[nn].y);
            pk.h[2] = __float2bfloat16(accs[nn].z);
            pk.h[3] = __float2bfloat16(accs[nn].w);
            *(uint2*)(h1 + (size_t)node * HID + col4) = pk.u;
        }
    }
}

// ---- K6b: bf16-input path (insurance; exits instantly when inputs are fp32) ----
__global__ __launch_bounds__(256) void k_gemm1_mfma(const __hip_bfloat16* __restrict__ x,
                                                    const unsigned short* __restrict__ W1,
                                                    const Flags* __restrict__ fl,
                                                    __hip_bfloat16* __restrict__ h1) {
    if (fl->f32) return;
    __shared__ unsigned short Wf[8192];
    int t = threadIdx.x;
    for (int i = t; i < 8192; i += 256) {
        int k = i >> 6;
        int n = i & 63;
        int kc = k >> 5, kr = k & 31;
        int q = kr >> 3, j = kr & 7;
        int n0 = n >> 4, col = n & 15;
        Wf[((((n0 << 2) | kc) << 2) | q) * 128 + col * 8 + j] = W1[i];
    }
    __syncthreads();
    int wave = t >> 6, lane = t & 63;
    int quad = lane >> 4, col = lane & 15;
    bf16x8 B[4][4];
#pragma unroll
    for (int n0 = 0; n0 < 4; ++n0)
#pragma unroll
        for (int kc = 0; kc < 4; ++kc)
            B[kc][n0] = *(const bf16x8*)&Wf[((((n0 << 2) | kc) << 2) | quad) * 128 + col * 8];
    int tile0 = (blockIdx.x * 4 + wave) * 4;
#pragma unroll 1
    for (int i = 0; i < 4; ++i) {
        int node0 = (tile0 + i) * 16;
        if (node0 >= NN) return;
        const __hip_bfloat16* xp = x + (size_t)(node0 + col) * FIN + quad * 8;
        f32x4 a0 = {0.f, 0.f, 0.f, 0.f}, a1 = a0, a2 = a0, a3 = a0;
#pragma unroll
        for (int kc = 0; kc < 4; ++kc) {
            bf16x8 A = *(const bf16x8*)(xp + kc * 32);
            a0 = __builtin_amdgcn_mfma_f32_16x16x32_bf16(A, B[kc][0], a0, 0, 0, 0);
            a1 = __builtin_amdgcn_mfma_f32_16x16x32_bf16(A, B[kc][1], a1, 0, 0, 0);
            a2 = __builtin_amdgcn_mfma_f32_16x16x32_bf16(A, B[kc][2], a2, 0, 0, 0);
            a3 = __builtin_amdgcn_mfma_f32_16x16x32_bf16(A, B[kc][3], a3, 0, 0, 0);
        }
        __hip_bfloat16* hp = h1 + (size_t)(node0 + quad * 4) * HID + col;
#pragma unroll
        for (int r = 0; r < 4; ++r) {
            hp[(size_t)r * HID + 0]  = __float2bfloat16(a0[r]);
            hp[(size_t)r * HID + 16] = __float2bfloat16(a1[r]);
            hp[(size_t)r * HID + 32] = __float2bfloat16(a2[r]);
            hp[(size_t)r * HID + 48] = __float2bfloat16(a3[r]);
        }
    }
}

// ---- K7: gather-aggregate layer 1, shfl-broadcast edge batching ----
__global__ __launch_bounds__(256) void k_agg1(const int* __restrict__ rowptrN,
                                              const int2* __restrict__ epack,
                                              const float* __restrict__ dinv1,
                                              const __hip_bfloat16* __restrict__ h1,
                                              const void* __restrict__ b1,
                                              const Flags* __restrict__ fl,
                                              float* __restrict__ out1) {
    int t = threadIdx.x;
    int n = blockIdx.x * 16 + (t >> 4);
    if (n >= NN) return;
    int l = t & 15;
    int f = l * 4;
    int wbase = t & 48;
    int f32 = fl->f32;
    float dn = dinv1[n];
    int p0 = rowptrN[n], p1 = rowptrN[n + 1];
    float a0 = 0.f, a1 = 0.f, a2 = 0.f, a3 = 0.f;
    for (int p = p0; p < p1; p += 16) {
        int idx = p + l;
        int2 ev = make_int2(0, 0);
        float cw = 0.f;
        if (idx < p1) {
            ev = epack[idx];
            cw = dinv1[ev.x] * __int_as_float(ev.y);
        }
        int cnt = p1 - p; if (cnt > 16) cnt = 16;
        for (int j = 0; j < cnt; ++j) {
            int   r = __shfl(ev.x, wbase + j);
            float c = __shfl(cw,   wbase + j);
            float x0, x1, x2, x3;
            ld4bf(h1 + (size_t)r * HID + f, x0, x1, x2, x3);
            a0 += c * x0; a1 += c * x1; a2 += c * x2; a3 += c * x3;
        }
    }
    float x0, x1, x2, x3;
    ld4bf(h1 + (size_t)n * HID + f, x0, x1, x2, x3);
    float s = dn * dn;
    float4 o;
    o.x = fmaxf(dn * a0 + s * x0 + ldf(b1, f + 0, f32), 0.f);
    o.y = fmaxf(dn * a1 + s * x1 + ldf(b1, f + 1, f32), 0.f);
    o.z = fmaxf(dn * a2 + s * x2 + ldf(b1, f + 2, f32), 0.f);
    o.w = fmaxf(dn * a3 + s * x3 + ldf(b1, f + 3, f32), 0.f);
    *(float4*)(out1 + (size_t)n * HID + f) = o;
}

// ---- K8: h2 = out1 @ W2 ----
__global__ __launch_bounds__(256) void k_gemm2(const float* __restrict__ out1,
                                               const void* __restrict__ W2,
                                               const Flags* __restrict__ fl,
                                               float* __restrict__ h2) {
    __shared__ float Ws[HID * COUT];
    int t = threadIdx.x;
    int f32 = fl->f32;
    for (int i = t; i < HID * COUT; i += 256) Ws[i] = ldf(W2, i, f32);
    __syncthreads();
    int node = blockIdx.x * 64 + (t >> 2);
    if (node >= NN) return;
    int o4 = (t & 3) * 4;
    const float* xr = out1 + (size_t)node * HID;
    float a0 = 0.f, a1 = 0.f, a2 = 0.f, a3 = 0.f;
#pragma unroll 4
    for (int k = 0; k < HID; ++k) {
        float xv = xr[k];
        const float* wr = &Ws[k * COUT + o4];
        a0 += xv * wr[0]; a1 += xv * wr[1]; a2 += xv * wr[2]; a3 += xv * wr[3];
    }
    float* ho = h2 + (size_t)node * COUT + o4;
    ho[0] = a0; ho[1] = a1; ho[2] = a2; ho[3] = a3;
}

// ---- K9: gather-aggregate layer 2, shfl-broadcast (4-lane groups) ----
__global__ __launch_bounds__(256) void k_agg2(const int* __restrict__ rowptrN,
                                              const int2* __restrict__ epack,
                                              const float* __restrict__ dinv2,
                                              const float* __restrict__ h2,
                                              const void* __restrict__ bias2,
                                              const Flags* __restrict__ fl,
                                              const int* __restrict__ delpos,
                                              void* __restrict__ out) {
    int t = threadIdx.x;
    int n = blockIdx.x * 64 + (t >> 2);
    if (n >= NN) return;
    int l = t & 3;
    int f = l * 4;
    int wbase = t & 60;
    int f32 = fl->f32;
    int dp = *delpos;
    float dn = dinv2[n];
    int p0 = rowptrN[n], p1 = rowptrN[n + 1];
    float a0 = 0.f, a1 = 0.f, a2 = 0.f, a3 = 0.f;
    for (int p = p0; p < p1; p += 4) {
        int idx = p + l;
        int rr = 0;
        float cw = 0.f;
        if (idx < p1) {
            int2 ev = epack[idx];
            float w = (idx == dp) ? 0.f : __int_as_float(ev.y);
            rr = ev.x;
            cw = dinv2[rr] * w;
        }
        int cnt = p1 - p; if (cnt > 4) cnt = 4;
        for (int j = 0; j < cnt; ++j) {
            int   r = __shfl(rr, wbase + j);
            float c = __shfl(cw, wbase + j);
            const float4 hv = *(const float4*)(h2 + (size_t)r * COUT + f);
            a0 += c * hv.x; a1 += c * hv.y; a2 += c * hv.z; a3 += c * hv.w;
        }
    }
    float s = dn * dn;
    const float4 hn = *(const float4*)(h2 + (size_t)n * COUT + f);
    float o0 = dn * a0 + s * hn.x + ldf(bias2, f + 0, f32);
    float o1 = dn * a1 + s * hn.y + ldf(bias2, f + 1, f32);
    float o2 = dn * a2 + s * hn.z + ldf(bias2, f + 2, f32);
    float o3 = dn * a3 + s * hn.w + ldf(bias2, f + 3, f32);
    size_t idx = (size_t)n * COUT + f;
    if (f32) {
        float* op = (float*)out + idx;
        op[0] = o0; op[1] = o1; op[2] = o2; op[3] = o3;
    } else {
        union { uint2 u; __hip_bfloat16 h[4]; } pk;
        pk.h[0] = __float2bfloat16(o0); pk.h[1] = __float2bfloat16(o1);
        pk.h[2] = __float2bfloat16(o2); pk.h[3] = __float2bfloat16(o3);
        *(uint2*)((__hip_bfloat16*)out + idx) = pk.u;
    }
}

extern "C" void kernel_launch(void* const* d_in, const int* in_sizes, int n_in,
                              void* d_out, int out_size, void* d_ws, size_t ws_size,
                              hipStream_t stream) {
    const void* x  = d_in[0];
    const void* ei = d_in[1];
    const void* ew = d_in[2];
    const void* W1 = d_in[3];
    const void* b1 = d_in[4];
    const void* W2 = d_in[5];
    const void* b2 = d_in[6];

    // workspace ~60 MB. tmp (16 MB) aliases out1 (25.6 MB): tmp dead after partB,
    // out1 first written by agg1 later — safe on a single stream.
    char* wsb = (char*)d_ws;
    float* dinv1    = (float*)wsb;                     wsb += (size_t)NN * 4;
    float* dinv2    = (float*)wsb;                     wsb += (size_t)NN * 4;
    float* deg      = (float*)wsb;                     wsb += (size_t)NN * 4;
    int*   rowptrN  = (int*)wsb;                       wsb += (size_t)(NN + 1) * 4;
    int*   cursorA  = (int*)wsb;                       wsb += (size_t)NBUK * 4;
    int*   bucketBase = (int*)wsb;                     wsb += (size_t)NBUK * 4;
    wsb = (char*)(((uintptr_t)wsb + 15) & ~(uintptr_t)15);
    int2*  epack    = (int2*)wsb;                      wsb += (size_t)NE * 8;
    __hip_bfloat16* h1 = (__hip_bfloat16*)wsb;         wsb += (size_t)NN * HID * 2;
    float* h2       = (float*)wsb;                     wsb += (size_t)NN * COUT * 4;
    long long* tmp  = (long long*)wsb;                 // NBUK*CAP*8 = 16.0 MB (alias out1)
    float* out1     = (float*)wsb;                     wsb += (size_t)NN * HID * 4;
    u64*   minkey   = (u64*)wsb;                       wsb += 8;
    Flags* fl       = (Flags*)wsb;                     wsb += 8;
    int*   delpos   = (int*)wsb;                       wsb += 8;

    hipMemsetAsync(cursorA, 0, (size_t)NBUK * 4, stream);
    hipMemsetAsync(minkey, 0xFF, 8, stream);
    hipMemsetAsync(delpos, 0xFF, 4, stream);

    k_detect<<<1, 64, 0, stream>>>((const unsigned short*)x, (const int*)ei, fl);
    k_mink<<<(NE + 255) / 256, 256, 0, stream>>>(ei, ew, fl, minkey);
    k_partA<<<PART_NB, 256, 0, stream>>>(ei, ew, fl, minkey, cursorA, tmp);
    k_scanBk<<<1, 512, 0, stream>>>(cursorA, bucketBase, rowptrN);
    k_partB<<<NBUK, 256, 0, stream>>>(cursorA, bucketBase, tmp, epack, rowptrN,
                                      deg, delpos);
    k_dinv<<<(NN + 255) / 256, 256, 0, stream>>>(deg, ei, ew, fl, minkey, dinv1, dinv2);
    k_gemm1_f32<<<(NN + 63) / 64, 256, 0, stream>>>((const float*)x, (const float*)W1,
                                                    fl, h1);
    k_gemm1_mfma<<<(NN / 16 + 15) / 16, 256, 0, stream>>>((const __hip_bfloat16*)x,
                                                          (const unsigned short*)W1, fl, h1);
    k_agg1<<<(NN + 15) / 16, 256, 0, stream>>>(rowptrN, epack, dinv1, h1, b1, fl, out1);
    k_gemm2<<<(NN + 63) / 64, 256, 0, stream>>>(out1, W2, fl, h2);
    k_agg2<<<(NN + 63) / 64, 256, 0, stream>>>(rowptrN, epack, dinv2, h2, b2, fl,
                                               delpos, d_out);
}